// Round 6
// baseline (159.715 us; speedup 1.0000x reference)
//
#include <hip/hip_runtime.h>
#include <hip/hip_bf16.h>

typedef __hip_bfloat16 bf16;
#define EPSF 1e-5f

// ---------------- K1: comp = relu(bn(conv1x1(x))) ----------------
// Block = 64-px tile x 32 oc (4 waves; wave = 8 wave-uniform oc x 64 px).
// x staged via double-buffered LDS chunks of 32ic x 64px (coalesced float4).
__global__ void k1_comp(const float* __restrict__ x, const float* __restrict__ w,
                        const float* __restrict__ gamma, const float* __restrict__ beta,
                        const float* __restrict__ mean, const float* __restrict__ var,
                        float* __restrict__ comp) {
    __shared__ float shx[2][32 * 64];           // 16 KB
    const int pxt = blockIdx.x;                 // 0..63
    const int ocg = blockIdx.y;                 // 0..1
    const int b   = blockIdx.z;
    const int tid  = threadIdx.x;
    const int wave = tid >> 6, lane = tid & 63;
    const int oc0 = ocg * 32 + wave * 8;        // wave-uniform
    const int px0 = pxt << 6;
    const float* xb = x + b * (256 * 4096) + px0;

    float acc[8] = {0.f, 0.f, 0.f, 0.f, 0.f, 0.f, 0.f, 0.f};

    #pragma unroll
    for (int i = 0; i < 2; ++i) {
        int f4  = tid * 2 + i;                  // 0..511
        int row = f4 >> 4, col4 = f4 & 15;
        float4 v = *(const float4*)(xb + row * 4096 + col4 * 4);
        *(float4*)(&shx[0][row * 64 + col4 * 4]) = v;
    }
    __syncthreads();

    for (int icc = 0; icc < 8; ++icc) {
        const int buf = icc & 1;
        if (icc < 7) {
            #pragma unroll
            for (int i = 0; i < 2; ++i) {
                int f4  = tid * 2 + i;
                int row = f4 >> 4, col4 = f4 & 15;
                float4 v = *(const float4*)(xb + ((icc + 1) * 32 + row) * 4096 + col4 * 4);
                *(float4*)(&shx[buf ^ 1][row * 64 + col4 * 4]) = v;
            }
        }
        #pragma unroll 8
        for (int ic_l = 0; ic_l < 32; ++ic_l) {
            float xv = shx[buf][ic_l * 64 + lane];
            const float* wp = w + icc * 32 + ic_l;      // + oc*256, uniform -> s_load
            #pragma unroll
            for (int m = 0; m < 8; ++m)
                acc[m] += xv * wp[(oc0 + m) * 256];
        }
        __syncthreads();
    }
    #pragma unroll
    for (int m = 0; m < 8; ++m) {
        int mo = oc0 + m;
        float s = gamma[mo] * rsqrtf(var[mo] + EPSF);
        float r = acc[m] * s + (beta[mo] - mean[mo] * s);
        comp[(b * 64 + mo) * 4096 + px0 + lane] = fmaxf(r, 0.f);
    }
}

// ---------------- K2: split-K conv3x3 partials, 2 px/thread ----------------
// Block = 16-row x 32-col pixel tile x 10 oc x ONE 16-ic chunk (split-K over 4).
// Thread (tx,ty) computes cols 2tx,2tx+1 of row ty: 12 taps -> 2x9 FMA per oc,
// halving per-FMA s_load pressure vs 1 px/thread. Plane stride 35 -> 2-way
// bank aliasing only (free). Grid (8, 40, 2) = 640 blocks, 2.5 blocks/CU.
__global__ void k2_enc_part(const float* __restrict__ comp, const float* __restrict__ w,
                            float* __restrict__ encp) {
    __shared__ float sh[16 * 630];              // 16 planes of 18x35 (34 used) = 40.3 KB
    const int tile = blockIdx.x;                // 0..7: 4 row-tiles x 2 col-tiles
    const int og   = blockIdx.y >> 2;           // 0..9
    const int icc  = blockIdx.y & 3;            // 0..3
    const int b    = blockIdx.z;
    const int ty0 = (tile >> 1) << 4;           // 0,16,32,48
    const int tx0 = (tile & 1) << 5;            // 0,32
    const int tid = threadIdx.x;
    const int tx = tid & 15, ty = tid >> 4;     // col-pair 0..15, row 0..15
    const int o0 = og * 10;

    // stage 16 planes of 18 rows x 34 cols (halo -1..+32 / -1..+16)
    const float* cb = comp + (b * 64 + icc * 16) * 4096;
    for (int idx = tid; idx < 16 * 612; idx += 256) {
        int ic_l = idx / 612;
        int rem  = idx - ic_l * 612;
        int r = rem / 34;
        int c = rem - r * 34;
        int gy = ty0 + r - 1;
        int gx = tx0 + c - 1;
        float v = 0.f;
        if (gy >= 0 && gy < 64 && gx >= 0 && gx < 64)
            v = cb[(ic_l << 12) + (gy << 6) + gx];
        sh[ic_l * 630 + r * 35 + c] = v;
    }
    __syncthreads();

    float accA[10], accB[10];
    #pragma unroll
    for (int i = 0; i < 10; ++i) { accA[i] = 0.f; accB[i] = 0.f; }

    #pragma unroll 2
    for (int ic_l = 0; ic_l < 16; ++ic_l) {
        const float* base = sh + ic_l * 630 + ty * 35 + 2 * tx;
        float t[3][4];
        #pragma unroll
        for (int dy = 0; dy < 3; ++dy)
            #pragma unroll
            for (int dx = 0; dx < 4; ++dx)
                t[dy][dx] = base[dy * 35 + dx];
        const int ic = icc * 16 + ic_l;
        #pragma unroll
        for (int o_l = 0; o_l < 10; ++o_l) {
            const float* wp = w + ((o0 + o_l) * 64 + ic) * 9;   // uniform -> s_load
            #pragma unroll
            for (int dy = 0; dy < 3; ++dy)
                #pragma unroll
                for (int dx = 0; dx < 3; ++dx) {
                    float wv = wp[dy * 3 + dx];
                    accA[o_l] += wv * t[dy][dx];
                    accB[o_l] += wv * t[dy][dx + 1];
                }
        }
    }
    const int pix = ((ty0 + ty) << 6) + tx0 + 2 * tx;
    #pragma unroll
    for (int o_l = 0; o_l < 10; ++o_l) {
        float2 v = {accA[o_l], accB[o_l]};
        *(float2*)(&encp[((icc * 2 + b) * 100 + o0 + o_l) * 4096 + pix]) = v;
    }
}

// ---------------- K3: sum partials + BN + pixel-shuffle + softmax (bf16 out) ----
// 512 blocks x 64 threads: 2 waves on every CU (was 128 blocks on half the CUs).
__global__ void k3_softmax(const float* __restrict__ encp,
                           const float* __restrict__ gamma, const float* __restrict__ beta,
                           const float* __restrict__ mean, const float* __restrict__ var,
                           bf16* __restrict__ Wsm) {
    int t = blockIdx.x * 64 + threadIdx.x;      // 32768 threads
    int pos = t & 4095;
    int g   = (t >> 12) & 3;
    int b   = t >> 14;
    float v[25];
    float mx = -1e30f;
    #pragma unroll
    for (int k = 0; k < 25; ++k) {
        int o = k * 4 + g;                       // wave-uniform -> s_loads for BN
        float a = 0.f;
        #pragma unroll
        for (int icc = 0; icc < 4; ++icc)
            a += encp[((icc * 2 + b) * 100 + o) * 4096 + pos];
        float s = gamma[o] * rsqrtf(var[o] + EPSF);
        v[k] = a * s + (beta[o] - mean[o] * s);
        mx = fmaxf(mx, v[k]);
    }
    float s = 0.f;
    #pragma unroll
    for (int k = 0; k < 25; ++k) { v[k] = __expf(v[k] - mx); s += v[k]; }
    float inv = 1.f / s;
    bf16* o = Wsm + ((b * 4 + g) * 25) * 4096 + pos;
    #pragma unroll
    for (int k = 0; k < 25; ++k) o[k * 4096] = __float2bfloat16(v[k] * inv);
}

// ---------------- K4: weighted gather ----------------
// Block: 16x8 low-res tile x 2 ph halves (256 threads). Thread owns (yl,xl,ph),
// both pw subpixels: 50 bf16 weight regs reused over 4 channel-quads.
__global__ void k4_gather(const float* __restrict__ x, const bf16* __restrict__ Wsm,
                          float* __restrict__ out) {
    __shared__ float4 patch[12 * 21];           // 12x20 used, pitch 21
    const int tile   = blockIdx.x;              // 0..31: tileY 0..7, tileX 0..3
    const int cchunk = blockIdx.y;              // 0..15 (16 channels each)
    const int b      = blockIdx.z;
    const int ly0 = (tile >> 2) << 3;
    const int lx0 = (tile & 3) << 4;
    const int tid = threadIdx.x;
    const int ph = tid >> 7;
    const int r  = tid & 127;
    const int ly = r >> 4, lx = r & 15;
    const int yl = ly0 + ly, xl = lx0 + lx;

    float w0[25], w1[25];
    {
        const bf16* wp0 = Wsm + ((b * 4 + ph * 2    ) * 25) * 4096 + yl * 64 + xl;
        const bf16* wp1 = Wsm + ((b * 4 + ph * 2 + 1) * 25) * 4096 + yl * 64 + xl;
        #pragma unroll
        for (int k = 0; k < 25; ++k) {
            w0[k] = __bfloat162float(wp0[k * 4096]);
            w1[k] = __bfloat162float(wp1[k * 4096]);
        }
    }
    const int pr = tid / 20, pc = tid % 20;
    const int gy = ly0 - 2 + pr, gx = lx0 - 2 + pc;
    const bool inb = (tid < 240) && (gy >= 0) && (gy < 64) && (gx >= 0) && (gx < 64);

    for (int cg = 0; cg < 4; ++cg) {
        const int c0 = cchunk * 16 + cg * 4;
        if (tid < 240) {
            float4 v = {0.f, 0.f, 0.f, 0.f};
            if (inb) {
                const float* xp = x + ((b * 256 + c0) * 4096) + gy * 64 + gx;
                v.x = xp[0]; v.y = xp[4096]; v.z = xp[8192]; v.w = xp[12288];
            }
            patch[pr * 21 + pc] = v;
        }
        __syncthreads();
        float4 a0 = {0.f, 0.f, 0.f, 0.f};
        float4 a1 = {0.f, 0.f, 0.f, 0.f};
        #pragma unroll
        for (int i = 0; i < 5; ++i) {
            #pragma unroll
            for (int j = 0; j < 5; ++j) {
                float4 xv = patch[(ly + i) * 21 + (lx + j)];
                float wa = w0[i * 5 + j], wb = w1[i * 5 + j];
                a0.x += wa * xv.x; a0.y += wa * xv.y; a0.z += wa * xv.z; a0.w += wa * xv.w;
                a1.x += wb * xv.x; a1.y += wb * xv.y; a1.z += wb * xv.z; a1.w += wb * xv.w;
            }
        }
        float* ob = out + (b * 256 + c0) * 16384 + (2 * yl + ph) * 128 + 2 * xl;
        float2 s0 = {a0.x, a1.x}; *(float2*)(ob)           = s0;
        float2 s1 = {a0.y, a1.y}; *(float2*)(ob + 16384)   = s1;
        float2 s2 = {a0.z, a1.z}; *(float2*)(ob + 32768)   = s2;
        float2 s3 = {a0.w, a1.w}; *(float2*)(ob + 49152)   = s3;
        __syncthreads();
    }
}

extern "C" void kernel_launch(void* const* d_in, const int* in_sizes, int n_in,
                              void* d_out, int out_size, void* d_ws, size_t ws_size,
                              hipStream_t stream) {
    const float* x          = (const float*)d_in[0];
    const float* comp_w     = (const float*)d_in[1];
    const float* comp_gamma = (const float*)d_in[2];
    const float* comp_beta  = (const float*)d_in[3];
    const float* comp_mean  = (const float*)d_in[4];
    const float* comp_var   = (const float*)d_in[5];
    const float* enc_w      = (const float*)d_in[6];
    const float* enc_gamma  = (const float*)d_in[7];
    const float* enc_beta   = (const float*)d_in[8];
    const float* enc_mean   = (const float*)d_in[9];
    const float* enc_var    = (const float*)d_in[10];
    float* out = (float*)d_out;

    float* ws   = (float*)d_ws;
    float* comp = ws;                             // 2*64*4096    =  524288 floats
    float* encp = ws + 524288;                    // 4*2*100*4096 = 3276800 floats
    bf16*  Wsm  = (bf16*)(ws + 524288 + 3276800); // 2*4*25*4096 bf16

    k1_comp<<<dim3(64, 2, 2), dim3(256), 0, stream>>>(x, comp_w, comp_gamma, comp_beta,
                                                      comp_mean, comp_var, comp);
    k2_enc_part<<<dim3(8, 40, 2), dim3(256), 0, stream>>>(comp, enc_w, encp);
    k3_softmax<<<dim3(512), dim3(64), 0, stream>>>(encp, enc_gamma, enc_beta,
                                                   enc_mean, enc_var, Wsm);
    k4_gather<<<dim3(32, 16, 2), dim3(256), 0, stream>>>(x, Wsm, out);
}

// Round 7
// 153.029 us; speedup vs baseline: 1.0437x; 1.0437x over previous
//
#include <hip/hip_runtime.h>
#include <hip/hip_bf16.h>

typedef __hip_bfloat16 bf16;
#define EPSF 1e-5f

// ---------------- K1: comp = relu(bn(conv1x1(x))) ----------------
// Block = 64-px tile x 32 oc (4 waves; wave = 8 wave-uniform oc x 64 px).
// x staged via double-buffered LDS chunks of 32ic x 64px (coalesced float4).
__global__ void k1_comp(const float* __restrict__ x, const float* __restrict__ w,
                        const float* __restrict__ gamma, const float* __restrict__ beta,
                        const float* __restrict__ mean, const float* __restrict__ var,
                        float* __restrict__ comp) {
    __shared__ float shx[2][32 * 64];           // 16 KB
    const int pxt = blockIdx.x;                 // 0..63
    const int ocg = blockIdx.y;                 // 0..1
    const int b   = blockIdx.z;
    const int tid  = threadIdx.x;
    const int wave = tid >> 6, lane = tid & 63;
    const int oc0 = ocg * 32 + wave * 8;        // wave-uniform
    const int px0 = pxt << 6;
    const float* xb = x + b * (256 * 4096) + px0;

    float acc[8] = {0.f, 0.f, 0.f, 0.f, 0.f, 0.f, 0.f, 0.f};

    #pragma unroll
    for (int i = 0; i < 2; ++i) {
        int f4  = tid * 2 + i;                  // 0..511
        int row = f4 >> 4, col4 = f4 & 15;
        float4 v = *(const float4*)(xb + row * 4096 + col4 * 4);
        *(float4*)(&shx[0][row * 64 + col4 * 4]) = v;
    }
    __syncthreads();

    for (int icc = 0; icc < 8; ++icc) {
        const int buf = icc & 1;
        if (icc < 7) {
            #pragma unroll
            for (int i = 0; i < 2; ++i) {
                int f4  = tid * 2 + i;
                int row = f4 >> 4, col4 = f4 & 15;
                float4 v = *(const float4*)(xb + ((icc + 1) * 32 + row) * 4096 + col4 * 4);
                *(float4*)(&shx[buf ^ 1][row * 64 + col4 * 4]) = v;
            }
        }
        #pragma unroll 8
        for (int ic_l = 0; ic_l < 32; ++ic_l) {
            float xv = shx[buf][ic_l * 64 + lane];
            const float* wp = w + icc * 32 + ic_l;      // + oc*256, uniform -> s_load
            #pragma unroll
            for (int m = 0; m < 8; ++m)
                acc[m] += xv * wp[(oc0 + m) * 256];
        }
        __syncthreads();
    }
    #pragma unroll
    for (int m = 0; m < 8; ++m) {
        int mo = oc0 + m;
        float s = gamma[mo] * rsqrtf(var[mo] + EPSF);
        float r = acc[m] * s + (beta[mo] - mean[mo] * s);
        comp[(b * 64 + mo) * 4096 + px0 + lane] = fmaxf(r, 0.f);
    }
}

// ---------------- K2: split-K conv3x3 partials, 2 px/thread, 5 oc/block ------
// Block = 16-row x 32-col tile x 5 oc x ONE 16-ic chunk (staged as 2x8 planes).
// Grid (8, 80, 2) = 1280 blocks -> 5 blocks/CU, 20 waves/CU. Weight slice per
// block = 5 oc x 16 ic x 9 x 4B = 2.88 KB; 5 resident slices = 14.4 KB < 16 KB
// K$ (R5 thrashed at 28.8 KB). LDS 20.2 KB (8 planes of 18x35) -> not the cap.
__global__ void k2_enc_part(const float* __restrict__ comp, const float* __restrict__ w,
                            float* __restrict__ encp) {
    __shared__ float sh[8 * 630];               // 8 planes of 18x35 (34 used) = 20.2 KB
    const int tile = blockIdx.x;                // 0..7: 4 row-tiles x 2 col-tiles
    const int og   = blockIdx.y >> 2;           // 0..19 (5 oc each)
    const int icc  = blockIdx.y & 3;            // 0..3  (16 ic each)
    const int b    = blockIdx.z;
    const int ty0 = (tile >> 1) << 4;           // 0,16,32,48
    const int tx0 = (tile & 1) << 5;            // 0,32
    const int tid = threadIdx.x;
    const int tx = tid & 15, ty = tid >> 4;     // col-pair 0..15, row 0..15
    const int o0 = og * 5;

    float accA[5], accB[5];
    #pragma unroll
    for (int i = 0; i < 5; ++i) { accA[i] = 0.f; accB[i] = 0.f; }

    for (int ics = 0; ics < 2; ++ics) {
        if (ics) __syncthreads();
        // stage 8 planes of 18 rows x 34 cols (halo -1..+16 / -1..+32)
        const float* cb = comp + (b * 64 + icc * 16 + ics * 8) * 4096;
        for (int idx = tid; idx < 8 * 612; idx += 256) {
            int ic_l = idx / 612;
            int rem  = idx - ic_l * 612;
            int r = rem / 34;
            int c = rem - r * 34;
            int gy = ty0 + r - 1;
            int gx = tx0 + c - 1;
            float v = 0.f;
            if (gy >= 0 && gy < 64 && gx >= 0 && gx < 64)
                v = cb[(ic_l << 12) + (gy << 6) + gx];
            sh[ic_l * 630 + r * 35 + c] = v;
        }
        __syncthreads();

        #pragma unroll 2
        for (int ic_l = 0; ic_l < 8; ++ic_l) {
            const float* base = sh + ic_l * 630 + ty * 35 + 2 * tx;
            float t[3][4];
            #pragma unroll
            for (int dy = 0; dy < 3; ++dy)
                #pragma unroll
                for (int dx = 0; dx < 4; ++dx)
                    t[dy][dx] = base[dy * 35 + dx];
            const int ic = icc * 16 + ics * 8 + ic_l;
            #pragma unroll
            for (int o_l = 0; o_l < 5; ++o_l) {
                const float* wp = w + ((o0 + o_l) * 64 + ic) * 9;   // uniform -> s_load
                #pragma unroll
                for (int dy = 0; dy < 3; ++dy)
                    #pragma unroll
                    for (int dx = 0; dx < 3; ++dx) {
                        float wv = wp[dy * 3 + dx];
                        accA[o_l] += wv * t[dy][dx];
                        accB[o_l] += wv * t[dy][dx + 1];
                    }
            }
        }
    }
    const int pix = ((ty0 + ty) << 6) + tx0 + 2 * tx;
    #pragma unroll
    for (int o_l = 0; o_l < 5; ++o_l) {
        float2 v = {accA[o_l], accB[o_l]};
        *(float2*)(&encp[((icc * 2 + b) * 100 + o0 + o_l) * 4096 + pix]) = v;
    }
}

// ---------------- K3: sum partials + BN + pixel-shuffle + softmax (bf16 out) ----
// 512 blocks x 64 threads: 2 waves on every CU.
__global__ void k3_softmax(const float* __restrict__ encp,
                           const float* __restrict__ gamma, const float* __restrict__ beta,
                           const float* __restrict__ mean, const float* __restrict__ var,
                           bf16* __restrict__ Wsm) {
    int t = blockIdx.x * 64 + threadIdx.x;      // 32768 threads
    int pos = t & 4095;
    int g   = (t >> 12) & 3;
    int b   = t >> 14;
    float v[25];
    float mx = -1e30f;
    #pragma unroll
    for (int k = 0; k < 25; ++k) {
        int o = k * 4 + g;                       // wave-uniform -> s_loads for BN
        float a = 0.f;
        #pragma unroll
        for (int icc = 0; icc < 4; ++icc)
            a += encp[((icc * 2 + b) * 100 + o) * 4096 + pos];
        float s = gamma[o] * rsqrtf(var[o] + EPSF);
        v[k] = a * s + (beta[o] - mean[o] * s);
        mx = fmaxf(mx, v[k]);
    }
    float s = 0.f;
    #pragma unroll
    for (int k = 0; k < 25; ++k) { v[k] = __expf(v[k] - mx); s += v[k]; }
    float inv = 1.f / s;
    bf16* o = Wsm + ((b * 4 + g) * 25) * 4096 + pos;
    #pragma unroll
    for (int k = 0; k < 25; ++k) o[k * 4096] = __float2bfloat16(v[k] * inv);
}

// ---------------- K4: weighted gather ----------------
// Block: 16x8 low-res tile x 2 ph halves (256 threads). Thread owns (yl,xl,ph),
// both pw subpixels: 50 bf16 weight regs reused over 4 channel-quads.
__global__ void k4_gather(const float* __restrict__ x, const bf16* __restrict__ Wsm,
                          float* __restrict__ out) {
    __shared__ float4 patch[12 * 21];           // 12x20 used, pitch 21
    const int tile   = blockIdx.x;              // 0..31: tileY 0..7, tileX 0..3
    const int cchunk = blockIdx.y;              // 0..15 (16 channels each)
    const int b      = blockIdx.z;
    const int ly0 = (tile >> 2) << 3;
    const int lx0 = (tile & 3) << 4;
    const int tid = threadIdx.x;
    const int ph = tid >> 7;
    const int r  = tid & 127;
    const int ly = r >> 4, lx = r & 15;
    const int yl = ly0 + ly, xl = lx0 + lx;

    float w0[25], w1[25];
    {
        const bf16* wp0 = Wsm + ((b * 4 + ph * 2    ) * 25) * 4096 + yl * 64 + xl;
        const bf16* wp1 = Wsm + ((b * 4 + ph * 2 + 1) * 25) * 4096 + yl * 64 + xl;
        #pragma unroll
        for (int k = 0; k < 25; ++k) {
            w0[k] = __bfloat162float(wp0[k * 4096]);
            w1[k] = __bfloat162float(wp1[k * 4096]);
        }
    }
    const int pr = tid / 20, pc = tid % 20;
    const int gy = ly0 - 2 + pr, gx = lx0 - 2 + pc;
    const bool inb = (tid < 240) && (gy >= 0) && (gy < 64) && (gx >= 0) && (gx < 64);

    for (int cg = 0; cg < 4; ++cg) {
        const int c0 = cchunk * 16 + cg * 4;
        if (tid < 240) {
            float4 v = {0.f, 0.f, 0.f, 0.f};
            if (inb) {
                const float* xp = x + ((b * 256 + c0) * 4096) + gy * 64 + gx;
                v.x = xp[0]; v.y = xp[4096]; v.z = xp[8192]; v.w = xp[12288];
            }
            patch[pr * 21 + pc] = v;
        }
        __syncthreads();
        float4 a0 = {0.f, 0.f, 0.f, 0.f};
        float4 a1 = {0.f, 0.f, 0.f, 0.f};
        #pragma unroll
        for (int i = 0; i < 5; ++i) {
            #pragma unroll
            for (int j = 0; j < 5; ++j) {
                float4 xv = patch[(ly + i) * 21 + (lx + j)];
                float wa = w0[i * 5 + j], wb = w1[i * 5 + j];
                a0.x += wa * xv.x; a0.y += wa * xv.y; a0.z += wa * xv.z; a0.w += wa * xv.w;
                a1.x += wb * xv.x; a1.y += wb * xv.y; a1.z += wb * xv.z; a1.w += wb * xv.w;
            }
        }
        float* ob = out + (b * 256 + c0) * 16384 + (2 * yl + ph) * 128 + 2 * xl;
        float2 s0 = {a0.x, a1.x}; *(float2*)(ob)           = s0;
        float2 s1 = {a0.y, a1.y}; *(float2*)(ob + 16384)   = s1;
        float2 s2 = {a0.z, a1.z}; *(float2*)(ob + 32768)   = s2;
        float2 s3 = {a0.w, a1.w}; *(float2*)(ob + 49152)   = s3;
        __syncthreads();
    }
}

extern "C" void kernel_launch(void* const* d_in, const int* in_sizes, int n_in,
                              void* d_out, int out_size, void* d_ws, size_t ws_size,
                              hipStream_t stream) {
    const float* x          = (const float*)d_in[0];
    const float* comp_w     = (const float*)d_in[1];
    const float* comp_gamma = (const float*)d_in[2];
    const float* comp_beta  = (const float*)d_in[3];
    const float* comp_mean  = (const float*)d_in[4];
    const float* comp_var   = (const float*)d_in[5];
    const float* enc_w      = (const float*)d_in[6];
    const float* enc_gamma  = (const float*)d_in[7];
    const float* enc_beta   = (const float*)d_in[8];
    const float* enc_mean   = (const float*)d_in[9];
    const float* enc_var    = (const float*)d_in[10];
    float* out = (float*)d_out;

    float* ws   = (float*)d_ws;
    float* comp = ws;                             // 2*64*4096    =  524288 floats
    float* encp = ws + 524288;                    // 4*2*100*4096 = 3276800 floats
    bf16*  Wsm  = (bf16*)(ws + 524288 + 3276800); // 2*4*25*4096 bf16

    k1_comp<<<dim3(64, 2, 2), dim3(256), 0, stream>>>(x, comp_w, comp_gamma, comp_beta,
                                                      comp_mean, comp_var, comp);
    k2_enc_part<<<dim3(8, 80, 2), dim3(256), 0, stream>>>(comp, enc_w, encp);
    k3_softmax<<<dim3(512), dim3(64), 0, stream>>>(encp, enc_gamma, enc_beta,
                                                   enc_mean, enc_var, Wsm);
    k4_gather<<<dim3(32, 16, 2), dim3(256), 0, stream>>>(x, Wsm, out);
}